// Round 10
// baseline (371.457 us; speedup 1.0000x reference)
//
#include <hip/hip_runtime.h>
#include <hip/hip_bf16.h>
#include <cstdint>

#define D_IN  4096
#define D_OUT 4096

typedef __attribute__((ext_vector_type(4)))  int   i32x4;

typedef const __attribute__((address_space(1))) unsigned g_u32;
typedef __attribute__((address_space(3))) unsigned       l_u32;

// ------- pass 1 (fused): blocks [0,1024) per-block max|W| -> atomicMax;
//         blocks [1024, ...) quantize x to int8 ------------------------------
__global__ void prep_kernel(const float* __restrict__ W, int nw,
                            const float* __restrict__ x,
                            char* __restrict__ xq,
                            const float* __restrict__ xscale, int nx,
                            unsigned* __restrict__ wsp) {
    int tid = threadIdx.x;
    if (blockIdx.x < 1024) {
        __shared__ float red[256];
        float m = 0.f;
        for (int i = (blockIdx.x * 256 + tid) * 4; i < nw; i += 1024 * 256 * 4) {
            float4 v = *(const float4*)(W + i);
            m = fmaxf(m, fmaxf(fmaxf(fabsf(v.x), fabsf(v.y)),
                               fmaxf(fabsf(v.z), fabsf(v.w))));
        }
        red[tid] = m; __syncthreads();
        for (int s = 128; s > 0; s >>= 1) {
            if (tid < s) red[tid] = fmaxf(red[tid], red[tid + s]);
            __syncthreads();
        }
        if (tid == 0) atomicMax(wsp, __float_as_uint(red[0]));
    } else {
        int i = ((blockIdx.x - 1024) * 256 + tid) * 4;
        if (i >= nx) return;
        float inv = 127.0f / fmaxf(xscale[0], 1e-8f);
        float4 v = *(const float4*)(x + i);
        char4 o;
        o.x = (char)fminf(fmaxf(rintf(v.x * inv), -127.f), 127.f);
        o.y = (char)fminf(fmaxf(rintf(v.y * inv), -127.f), 127.f);
        o.z = (char)fminf(fmaxf(rintf(v.z * inv), -127.f), 127.f);
        o.w = (char)fminf(fmaxf(rintf(v.w * inv), -127.f), 127.f);
        *(char4*)(xq + i) = o;
    }
}

// ------- pass 2: W (K x N) -> int8 transposed Wt (N x K), vectorized --------
__global__ void convW_kernel(const float* __restrict__ W,
                             char* __restrict__ Wt,
                             const unsigned* __restrict__ wsp) {
    __shared__ float tile[64][65];
    const float wmax = __uint_as_float(wsp[0]);
    const float inv  = 127.0f / wmax;
    const int n0 = blockIdx.x * 64, k0 = blockIdx.y * 64;
    const int t = threadIdx.x;
    {
        const int r = t >> 2, c0 = (t & 3) * 16;
        const float* src = W + (size_t)(k0 + r) * D_OUT + n0 + c0;
#pragma unroll
        for (int j = 0; j < 4; ++j) {
            float4 v = *(const float4*)(src + j * 4);
            tile[r][c0 + j * 4 + 0] = v.x;
            tile[r][c0 + j * 4 + 1] = v.y;
            tile[r][c0 + j * 4 + 2] = v.z;
            tile[r][c0 + j * 4 + 3] = v.w;
        }
    }
    __syncthreads();
    {
        const int n = t >> 2, kc = (t & 3) * 16;
        int4 pk;
        int* pw = (int*)&pk;
#pragma unroll
        for (int w = 0; w < 4; ++w) {
            unsigned word = 0;
#pragma unroll
            for (int j = 0; j < 4; ++j) {
                int q = (int)rintf(tile[kc + w * 4 + j][n] * inv);
                word |= ((unsigned)(unsigned char)(char)q) << (8 * j);
            }
            pw[w] = (int)word;
        }
        *(int4*)(Wt + (size_t)(n0 + n) * D_IN + k0 + kc) = pk;
    }
}

// ------- pass 3: 256x128 int8 GEMM, A direct-to-reg, B-only LDS ------------
// A:[M][K] i8, Bt:[N][K] i8, C = i32acc * (sx*ws) + bias.  BK=128, NT=32.
// A fragments (16 B/lane contiguous) load global->VGPR ping-pong banks,
// prefetched one full K-tile ahead; only B staged in LDS (16 KB/tile, dbuf).
// This removes A's LDS reads (128 KB/tile/CU) + writes -> LDS pipe ~1/3 of
// MFMA pipe, so pipe-sum shrinks even without better overlap.
// vmcnt ledger (issue order fixed: ...STAGEB(t+1)@KT(t-1) after LOADA(t)):
//   at KT(t) top, outstanding = {A(t) x8, B(t+1) x2} -> vmcnt(2);
//   t==NT-1 (no B(t+1) staged) -> vmcnt(0).
// Per tile: {bar; vmcnt; ds_read B x8; LOADA(t+1) x8 -> other bank; lgkm0;
//            32 MFMA on current bank; bar; STAGEB(t+2)->cur}.
// B swizzle identical to proven R4 path (chunk XOR row&7; measured 0 conf).
__global__ __launch_bounds__(512, 2)
void gemm_kernel(const char* __restrict__ A,
                 const char* __restrict__ Bt,
                 const float* __restrict__ bias,
                 const float* __restrict__ xscale,
                 const unsigned* __restrict__ wsp,
                 float* __restrict__ C, int M) {
    constexpr int K = D_IN, N = D_OUT;
    constexpr int NT = K / 128;                // 32 K-tiles of 128 B
    __shared__ char lds[2 * 16384];            // B only: 128 rows x 128 B, dbuf

    const int tid  = threadIdx.x;
    const int lane = tid & 63;
    const int wid  = tid >> 6;
    const int wr   = wid >> 1;                 // 0..3  (M)
    const int wc   = wid & 1;                  // 0..1  (N)

    // bijective XCD-aware block swizzle
    const int nTn = N / 128;                   // 32
    const int nwg = gridDim.x;                 // 1024
    int bid = blockIdx.x;
    int q8 = nwg >> 3, r8 = nwg & 7;
    int xcd = bid & 7, idx = bid >> 3;
    int swz = (xcd < r8 ? xcd * (q8 + 1) : r8 * (q8 + 1) + (xcd - r8) * q8) + idx;
    const int tm = swz / nTn, tn = swz % nTn;
    const int row0 = tm * 256, col0 = tn * 128;

    // B staging: LDS dest LINEAR; XOR involution sw = p ^ ((p>>7)&7)<<4 on
    // the global SOURCE, matched by swizzled ds_reads.
    int srcOff[2], dstOff[2];
#pragma unroll
    for (int i = 0; i < 2; ++i) {
        int p  = (i * 512 + tid) * 16;         // [0, 16384)
        int sw = p ^ (((p >> 7) & 7) << 4);
        dstOff[i] = p;
        srcOff[i] = (sw >> 7) * K + (sw & 127);
    }

    const char* srcB = Bt + (size_t)col0 * K;
    char* b0 = lds;
    char* b1 = lds + 16384;

    auto STAGEB = [&](int t, char* buf) {      // 16 KB: B rows 128 x 128 B
#pragma unroll
        for (int i = 0; i < 2; ++i)
            __builtin_amdgcn_global_load_lds((g_u32*)(srcB + t * 128 + srcOff[i]),
                                             (l_u32*)(buf + dstOff[i]), 16, 0, 0);
    };

    // A per-lane global base: row = row0 + wr*64 + m*16 + (lane&15),
    // byte col = t*128 + ks*64 + (lane>>4)*16  (16 B contiguous per lane)
    const char* aG = A + ((size_t)(row0 + wr * 64 + (lane & 15))) * K
                       + ((lane >> 4) * 16);

    auto LOADA = [&](int t, i32x4 (&dst)[4][2]) {
#pragma unroll
        for (int m = 0; m < 4; ++m)
#pragma unroll
            for (int ks = 0; ks < 2; ++ks)
                dst[m][ks] = *(const i32x4*)(aG + (size_t)m * 16 * K + t * 128 + ks * 64);
    };

    // B read addressing: row = wc*64 + n*16 + (lane&15); logical chunk
    // lc = ks*4 + (lane>>4); physical chunk = lc ^ (row&7) = lc ^ (lane&7).
    const int cp0 = (((lane >> 4) ^ (lane & 7)) << 4);
    const int cp1 = cp0 ^ 64;
    const int bRow = (wc * 64 + (lane & 15)) * 128;

    i32x4 acc[4][4];
#pragma unroll
    for (int m = 0; m < 4; ++m)
#pragma unroll
        for (int n = 0; n < 4; ++n) acc[m][n] = (i32x4){0, 0, 0, 0};

    i32x4 aP[4][2], aN[4][2];

    // ---- prologue: issue order defines the vmcnt ledger ----
    STAGEB(0, b0);          // B(0) x2
    LOADA(0, aP);           // A(0) x8
    STAGEB(1, b1);          // B(1) x2   -> outstanding 12

    auto KT = [&](int t, char* cur, i32x4 (&aUse)[4][2], i32x4 (&aLoad)[4][2],
                  bool last) {
        __builtin_amdgcn_s_barrier();
        if (last) { asm volatile("s_waitcnt vmcnt(0)" ::: "memory"); }
        else      { asm volatile("s_waitcnt vmcnt(2)" ::: "memory"); }

        i32x4 b[4][2];
#pragma unroll
        for (int n = 0; n < 4; ++n) {
            b[n][0] = *(const i32x4*)(cur + bRow + n * 2048 + cp0);
            b[n][1] = *(const i32x4*)(cur + bRow + n * 2048 + cp1);
        }
        if (t + 1 < NT) LOADA(t + 1, aLoad);

        asm volatile("s_waitcnt lgkmcnt(0)" ::: "memory");
        __builtin_amdgcn_s_setprio(1);
#pragma unroll
        for (int m = 0; m < 4; ++m)
#pragma unroll
            for (int n = 0; n < 4; ++n) {
                acc[m][n] = __builtin_amdgcn_mfma_i32_16x16x64_i8(aUse[m][0], b[n][0], acc[m][n], 0, 0, 0);
                acc[m][n] = __builtin_amdgcn_mfma_i32_16x16x64_i8(aUse[m][1], b[n][1], acc[m][n], 0, 0, 0);
            }
        __builtin_amdgcn_s_setprio(0);

        __builtin_amdgcn_s_barrier();
        if (t + 2 < NT) STAGEB(t + 2, cur);    // all waves past their reads
    };

    for (int t = 0; t < NT; t += 2) {
        KT(t,     b0, aP, aN, false);
        KT(t + 1, b1, aN, aP, t + 1 == NT - 1);
    }

    // ---- epilogue: C = acc * (sx*ws) + bias ----
    const float wmax  = __uint_as_float(wsp[0]);
    const float scale = (fmaxf(xscale[0], 1e-8f) * (1.0f / 127.0f)) * (wmax * (1.0f / 127.0f));
    const int lr = (lane >> 4) * 4, lc = lane & 15;
#pragma unroll
    for (int n = 0; n < 4; ++n) {
        int col = col0 + wc * 64 + n * 16 + lc;
        float bv = bias[col];
#pragma unroll
        for (int m = 0; m < 4; ++m) {
            int rowb = row0 + wr * 64 + m * 16 + lr;
            i32x4 v = acc[m][n];
#pragma unroll
            for (int r2 = 0; r2 < 4; ++r2)
                C[(size_t)(rowb + r2) * N + col] = (float)v[r2] * scale + bv;
        }
    }
}

extern "C" void kernel_launch(void* const* d_in, const int* in_sizes, int n_in,
                              void* d_out, int out_size, void* d_ws, size_t ws_size,
                              hipStream_t stream) {
    const float* x      = (const float*)d_in[0];   // [4,2048,4096] f32
    const float* W      = (const float*)d_in[1];   // [4096,4096] f32
    const float* xscale = (const float*)d_in[2];   // scalar
    const float* bias   = (const float*)d_in[3];   // [4096] f32
    float* out = (float*)d_out;

    const int nx = in_sizes[0];            // 33554432
    const int nw = in_sizes[1];            // 16777216
    const int M  = nx / D_IN;              // 8192

    char*     xq  = (char*)d_ws;                               // 32 MiB
    char*     Wt  = (char*)d_ws + (size_t)nx;                  // 16 MiB
    unsigned* wsp = (unsigned*)((char*)d_ws + (size_t)nx + nw);// 4 B

    hipMemsetAsync(wsp, 0, 4, stream);

    int qblocks = nx / 4 / 256;            // 32768
    prep_kernel<<<1024 + qblocks, 256, 0, stream>>>(W, nw, x, xq, xscale, nx, wsp);

    dim3 tb(256);
    dim3 tg(D_OUT / 64, D_IN / 64);        // 64 x 64
    convW_kernel<<<tg, tb, 0, stream>>>(W, Wt, wsp);

    int grid = (M / 256) * (D_OUT / 128);  // 1024
    gemm_kernel<<<grid, 512, 0, stream>>>(xq, Wt, bias, xscale, wsp, out, M);
}

// Round 11
// 200.843 us; speedup vs baseline: 1.8495x; 1.8495x over previous
//
#include <hip/hip_runtime.h>
#include <hip/hip_bf16.h>
#include <cstdint>

#define D_IN  4096
#define D_OUT 4096

typedef __attribute__((ext_vector_type(4)))  int   i32x4;

typedef const __attribute__((address_space(1))) unsigned g_u32;
typedef __attribute__((address_space(3))) unsigned       l_u32;

// ------- pass 1 (fused): blocks [0,1024) per-block max|W| -> atomicMax;
//         blocks [1024, ...) quantize x to int8 ------------------------------
// |W| >= 0 so float bit-pattern order == float order; atomicMax on uint is
// order-independent -> deterministic. wsp is zeroed per launch via memsetAsync.
__global__ void prep_kernel(const float* __restrict__ W, int nw,
                            const float* __restrict__ x,
                            char* __restrict__ xq,
                            const float* __restrict__ xscale, int nx,
                            unsigned* __restrict__ wsp) {
    int tid = threadIdx.x;
    if (blockIdx.x < 1024) {
        __shared__ float red[256];
        float m = 0.f;
        for (int i = (blockIdx.x * 256 + tid) * 4; i < nw; i += 1024 * 256 * 4) {
            float4 v = *(const float4*)(W + i);
            m = fmaxf(m, fmaxf(fmaxf(fabsf(v.x), fabsf(v.y)),
                               fmaxf(fabsf(v.z), fabsf(v.w))));
        }
        red[tid] = m; __syncthreads();
        for (int s = 128; s > 0; s >>= 1) {
            if (tid < s) red[tid] = fmaxf(red[tid], red[tid + s]);
            __syncthreads();
        }
        if (tid == 0) atomicMax(wsp, __float_as_uint(red[0]));
    } else {
        int i = ((blockIdx.x - 1024) * 256 + tid) * 4;
        if (i >= nx) return;
        float inv = 127.0f / fmaxf(xscale[0], 1e-8f);
        float4 v = *(const float4*)(x + i);
        char4 o;
        o.x = (char)fminf(fmaxf(rintf(v.x * inv), -127.f), 127.f);
        o.y = (char)fminf(fmaxf(rintf(v.y * inv), -127.f), 127.f);
        o.z = (char)fminf(fmaxf(rintf(v.z * inv), -127.f), 127.f);
        o.w = (char)fminf(fmaxf(rintf(v.w * inv), -127.f), 127.f);
        *(char4*)(xq + i) = o;
    }
}

// ------- pass 2: W (K x N) -> int8 transposed Wt (N x K), vectorized --------
// 64x64 tile per 256-thread block. Loads: 64B/thread contiguous f32; LDS
// [64][65] transpose (2-way bank = free); stores: packed 16B char16.
// W values are exact multiples of ws = max|W|/127; rint recovers the code.
__global__ void convW_kernel(const float* __restrict__ W,
                             char* __restrict__ Wt,
                             const unsigned* __restrict__ wsp) {
    __shared__ float tile[64][65];
    const float wmax = __uint_as_float(wsp[0]);
    const float inv  = 127.0f / wmax;
    const int n0 = blockIdx.x * 64, k0 = blockIdx.y * 64;
    const int t = threadIdx.x;
    {
        const int r = t >> 2, c0 = (t & 3) * 16;
        const float* src = W + (size_t)(k0 + r) * D_OUT + n0 + c0;
#pragma unroll
        for (int j = 0; j < 4; ++j) {
            float4 v = *(const float4*)(src + j * 4);
            tile[r][c0 + j * 4 + 0] = v.x;
            tile[r][c0 + j * 4 + 1] = v.y;
            tile[r][c0 + j * 4 + 2] = v.z;
            tile[r][c0 + j * 4 + 3] = v.w;
        }
    }
    __syncthreads();
    {
        const int n = t >> 2, kc = (t & 3) * 16;
        int4 pk;
        int* pw = (int*)&pk;
#pragma unroll
        for (int w = 0; w < 4; ++w) {
            unsigned word = 0;
#pragma unroll
            for (int j = 0; j < 4; ++j) {
                int q = (int)rintf(tile[kc + w * 4 + j][n] * inv);
                word |= ((unsigned)(unsigned char)(char)q) << (8 * j);
            }
            pw[w] = (int)word;
        }
        *(int4*)(Wt + (size_t)(n0 + n) * D_IN + k0 + kc) = pk;
    }
}

// ------- pass 3: 256x256 int8 GEMM, 2-region K-tile (frozen R4/R7/R8) ------
// A : [M][K] i8, Bt : [N][K] i8, C : [M][N] f32 = i32acc * (sx*ws) + bias.
// BK = 128 i8 elems = 128 B rows; NT = 32.
//  R1 (compute): barrier | STAGE B1(t+1)->nxt | ds_read b01,a03,b23 | Q1,Q2
//                | ds_read a47 (reuse regs) | Q3,Q4
//  R2 (publish): barrier | STAGE B0(t+2),A(t+2)->cur | s_waitcnt vmcnt(6)
// vmcnt(6) leaves exactly {B0(t+2),A(t+2)}: tile t+1 fully resident.
// Read swizzle: chunk = (lane>>4) ^ (lane&7); per quarter-wave covers all 8
// 16B-chunks of a 128B row -> conflict-free (measured 0).
__global__ __launch_bounds__(512, 2)
void gemm_kernel(const char* __restrict__ A,
                 const char* __restrict__ Bt,
                 const float* __restrict__ bias,
                 const float* __restrict__ xscale,
                 const unsigned* __restrict__ wsp,
                 float* __restrict__ C, int M) {
    constexpr int K = D_IN, N = D_OUT;         // byte stride per row = K (i8)
    constexpr int NT = K / 128;                // 32 K-tiles of 128 elems
    __shared__ char lds[2 * 65536];            // 2 x (A 32KiB + B 32KiB)

    const int tid  = threadIdx.x;
    const int lane = tid & 63;
    const int wid  = tid >> 6;
    const int wr   = wid >> 2;                 // 0..1  (M)
    const int wc   = wid & 3;                  // 0..3  (N)

    // bijective XCD-aware block swizzle
    const int nTn = N / 256;
    const int nwg = gridDim.x;
    int bid = blockIdx.x;
    int q8 = nwg >> 3, r8 = nwg & 7;
    int xcd = bid & 7, idx = bid >> 3;
    int swz = (xcd < r8 ? xcd * (q8 + 1) : r8 * (q8 + 1) + (xcd - r8) * q8) + idx;
    const int tm = swz / nTn, tn = swz % nTn;
    const int row0 = tm * 256, col0 = tn * 256;

    // staging: LDS dest LINEAR; XOR involution sw = p ^ ((p>>7)&7)<<4 applied
    // to the global SOURCE address, matched by swizzled ds_reads.
    int srcOff[4], dstOff[4];
#pragma unroll
    for (int i = 0; i < 4; ++i) {
        int p  = (i * 512 + tid) * 16;
        int sw = p ^ (((p >> 7) & 7) << 4);
        dstOff[i] = p;
        srcOff[i] = (sw >> 7) * K + (sw & 127);
    }

    const char* srcA = A  + (size_t)row0 * K;
    const char* srcB = Bt + (size_t)col0 * K;
    char* ldsb = lds;

    auto STAGE4 = [&](const char* src, char* dst) {
#pragma unroll
        for (int i = 0; i < 4; ++i)
            __builtin_amdgcn_global_load_lds((g_u32*)(src + srcOff[i]),
                                             (l_u32*)(dst + dstOff[i]), 16, 0, 0);
    };
    auto STAGE2 = [&](const char* src, char* dst) {
#pragma unroll
        for (int i = 0; i < 2; ++i)
            __builtin_amdgcn_global_load_lds((g_u32*)(src + srcOff[i]),
                                             (l_u32*)(dst + dstOff[i]), 16, 0, 0);
    };

    // ---- prologue: tile0 full (8 loads) + tile1 {B0, A} (6 loads) ----
    STAGE2(srcB, ldsb + 32768);                        // B0(0) -> buf0
    STAGE4(srcA, ldsb);                                // A(0)  -> buf0
    STAGE2(srcB + 128 * K, ldsb + 32768 + 16384);      // B1(0) -> buf0
    STAGE2(srcB + 128,     ldsb + 65536 + 32768);      // B0(1) -> buf1
    STAGE4(srcA + 128,     ldsb + 65536);              // A(1)  -> buf1

    i32x4 acc[8][4];
#pragma unroll
    for (int m = 0; m < 8; ++m)
#pragma unroll
        for (int n = 0; n < 4; ++n) acc[m][n] = (i32x4){0, 0, 0, 0};

    // swizzled per-lane read bases (chunk XOR covers row&7)
    const int cp0 = (((lane >> 4) << 4)) ^ ((lane & 7) << 4);
    const int cp1 = cp0 ^ 64;                          // k-half 1
    const int aBase = (wr * 128 + (lane & 15)) * 128;
    const int bBase = (wc * 64  + (lane & 15)) * 128;

    asm volatile("s_waitcnt vmcnt(6)" ::: "memory");   // tile0 resident

    auto KITER = [&](int t, char* cur, char* nxt) {
        i32x4 a[4][2], b01[2][2], b23[2][2];
        const char* cA = cur;
        const char* cB = cur + 32768;

        // ================= region 1: compute =================
        __builtin_amdgcn_s_barrier();
        if (t + 1 < NT) STAGE2(srcB + 128 * K + (t + 1) * 128, nxt + 32768 + 16384);

#pragma unroll
        for (int n = 0; n < 2; ++n) {
            b01[n][0] = *(const i32x4*)(cB + bBase + n * 2048 + cp0);
            b01[n][1] = *(const i32x4*)(cB + bBase + n * 2048 + cp1);
        }
#pragma unroll
        for (int m = 0; m < 4; ++m) {
            a[m][0] = *(const i32x4*)(cA + aBase + m * 2048 + cp0);
            a[m][1] = *(const i32x4*)(cA + aBase + m * 2048 + cp1);
        }
#pragma unroll
        for (int n = 0; n < 2; ++n) {
            b23[n][0] = *(const i32x4*)(cB + bBase + 4096 + n * 2048 + cp0);
            b23[n][1] = *(const i32x4*)(cB + bBase + 4096 + n * 2048 + cp1);
        }

        __builtin_amdgcn_s_setprio(1);
        // Q1: (m0-3, n0-1)
#pragma unroll
        for (int m = 0; m < 4; ++m)
#pragma unroll
            for (int n = 0; n < 2; ++n) {
                acc[m][n] = __builtin_amdgcn_mfma_i32_16x16x64_i8(a[m][0], b01[n][0], acc[m][n], 0, 0, 0);
                acc[m][n] = __builtin_amdgcn_mfma_i32_16x16x64_i8(a[m][1], b01[n][1], acc[m][n], 0, 0, 0);
            }
        // Q2: (m0-3, n2-3)
#pragma unroll
        for (int m = 0; m < 4; ++m)
#pragma unroll
            for (int n = 0; n < 2; ++n) {
                acc[m][n + 2] = __builtin_amdgcn_mfma_i32_16x16x64_i8(a[m][0], b23[n][0], acc[m][n + 2], 0, 0, 0);
                acc[m][n + 2] = __builtin_amdgcn_mfma_i32_16x16x64_i8(a[m][1], b23[n][1], acc[m][n + 2], 0, 0, 0);
            }
        // reload A rows 4-7 (reuse registers)
#pragma unroll
        for (int m = 0; m < 4; ++m) {
            a[m][0] = *(const i32x4*)(cA + aBase + 8192 + m * 2048 + cp0);
            a[m][1] = *(const i32x4*)(cA + aBase + 8192 + m * 2048 + cp1);
        }
        // Q3: (m4-7, n2-3)
#pragma unroll
        for (int m = 0; m < 4; ++m)
#pragma unroll
            for (int n = 0; n < 2; ++n) {
                acc[m + 4][n + 2] = __builtin_amdgcn_mfma_i32_16x16x64_i8(a[m][0], b23[n][0], acc[m + 4][n + 2], 0, 0, 0);
                acc[m + 4][n + 2] = __builtin_amdgcn_mfma_i32_16x16x64_i8(a[m][1], b23[n][1], acc[m + 4][n + 2], 0, 0, 0);
            }
        // Q4: (m4-7, n0-1)
#pragma unroll
        for (int m = 0; m < 4; ++m)
#pragma unroll
            for (int n = 0; n < 2; ++n) {
                acc[m + 4][n] = __builtin_amdgcn_mfma_i32_16x16x64_i8(a[m][0], b01[n][0], acc[m + 4][n], 0, 0, 0);
                acc[m + 4][n] = __builtin_amdgcn_mfma_i32_16x16x64_i8(a[m][1], b01[n][1], acc[m + 4][n], 0, 0, 0);
            }
        __builtin_amdgcn_s_setprio(0);

        // ================= region 2: publish =================
        __builtin_amdgcn_s_barrier();
        if (t + 2 < NT) {
            STAGE2(srcB + (t + 2) * 128, cur + 32768);     // B0(t+2) -> cur
            STAGE4(srcA + (t + 2) * 128, cur);             // A (t+2) -> cur
            asm volatile("s_waitcnt vmcnt(6)" ::: "memory");
        } else {
            asm volatile("s_waitcnt vmcnt(0)" ::: "memory");
        }
    };

    for (int t = 0; t < NT; t += 2) {
        KITER(t,     ldsb,         ldsb + 65536);
        KITER(t + 1, ldsb + 65536, ldsb);
    }

    // ---- epilogue: C = acc * (sx*ws) + bias, ws = max|W|/127 ----
    const float wmax  = __uint_as_float(wsp[0]);
    const float scale = (fmaxf(xscale[0], 1e-8f) * (1.0f / 127.0f)) * (wmax * (1.0f / 127.0f));
    const int lr = (lane >> 4) * 4, lc = lane & 15;
#pragma unroll
    for (int n = 0; n < 4; ++n) {
        int col = col0 + wc * 64 + n * 16 + lc;
        float bv = bias[col];
#pragma unroll
        for (int m = 0; m < 8; ++m) {
            int rowb = row0 + wr * 128 + m * 16 + lr;
            i32x4 v = acc[m][n];
#pragma unroll
            for (int r2 = 0; r2 < 4; ++r2)
                C[(size_t)(rowb + r2) * N + col] = (float)v[r2] * scale + bv;
        }
    }
}

extern "C" void kernel_launch(void* const* d_in, const int* in_sizes, int n_in,
                              void* d_out, int out_size, void* d_ws, size_t ws_size,
                              hipStream_t stream) {
    const float* x      = (const float*)d_in[0];   // [4,2048,4096] f32
    const float* W      = (const float*)d_in[1];   // [4096,4096] f32
    const float* xscale = (const float*)d_in[2];   // scalar
    const float* bias   = (const float*)d_in[3];   // [4096] f32
    float* out = (float*)d_out;

    const int nx = in_sizes[0];            // 33554432
    const int nw = in_sizes[1];            // 16777216
    const int M  = nx / D_IN;              // 8192

    char*     xq  = (char*)d_ws;                               // 32 MiB
    char*     Wt  = (char*)d_ws + (size_t)nx;                  // 16 MiB
    unsigned* wsp = (unsigned*)((char*)d_ws + (size_t)nx + nw);// 4 B

    // re-init the atomic max target every launch (deterministic; graph-safe)
    hipMemsetAsync(wsp, 0, 4, stream);

    int qblocks = nx / 4 / 256;            // 32768
    prep_kernel<<<1024 + qblocks, 256, 0, stream>>>(W, nw, x, xq, xscale, nx, wsp);

    dim3 tb(256);
    dim3 tg(D_OUT / 64, D_IN / 64);        // 64 x 64
    convW_kernel<<<tg, tb, 0, stream>>>(W, Wt, wsp);

    int grid = (M / 256) * (D_OUT / 256);  // 512
    gemm_kernel<<<grid, 512, 0, stream>>>(xq, Wt, bias, xscale, wsp, out, M);
}

// Round 14
// 200.387 us; speedup vs baseline: 1.8537x; 1.0023x over previous
//
#include <hip/hip_runtime.h>
#include <hip/hip_bf16.h>
#include <cstdint>

#define D_IN  4096
#define D_OUT 4096

typedef __attribute__((ext_vector_type(4)))  int   i32x4;

typedef const __attribute__((address_space(1))) unsigned g_u32;
typedef __attribute__((address_space(3))) unsigned       l_u32;

// ------- pass 1 (fused): blocks [0,1024) per-block max|W| -> atomicMax;
//         blocks [1024, ...) quantize x to int8 ------------------------------
__global__ void prep_kernel(const float* __restrict__ W, int nw,
                            const float* __restrict__ x,
                            char* __restrict__ xq,
                            const float* __restrict__ xscale, int nx,
                            unsigned* __restrict__ wsp) {
    int tid = threadIdx.x;
    if (blockIdx.x < 1024) {
        __shared__ float red[256];
        float m = 0.f;
        for (int i = (blockIdx.x * 256 + tid) * 4; i < nw; i += 1024 * 256 * 4) {
            float4 v = *(const float4*)(W + i);
            m = fmaxf(m, fmaxf(fmaxf(fabsf(v.x), fabsf(v.y)),
                               fmaxf(fabsf(v.z), fabsf(v.w))));
        }
        red[tid] = m; __syncthreads();
        for (int s = 128; s > 0; s >>= 1) {
            if (tid < s) red[tid] = fmaxf(red[tid], red[tid + s]);
            __syncthreads();
        }
        if (tid == 0) atomicMax(wsp, __float_as_uint(red[0]));
    } else {
        int i = ((blockIdx.x - 1024) * 256 + tid) * 4;
        if (i >= nx) return;
        float inv = 127.0f / fmaxf(xscale[0], 1e-8f);
        float4 v = *(const float4*)(x + i);
        char4 o;
        o.x = (char)fminf(fmaxf(rintf(v.x * inv), -127.f), 127.f);
        o.y = (char)fminf(fmaxf(rintf(v.y * inv), -127.f), 127.f);
        o.z = (char)fminf(fmaxf(rintf(v.z * inv), -127.f), 127.f);
        o.w = (char)fminf(fmaxf(rintf(v.w * inv), -127.f), 127.f);
        *(char4*)(xq + i) = o;
    }
}

// ------- pass 2: W (K x N) -> int8 transposed Wt (N x K), vectorized --------
__global__ void convW_kernel(const float* __restrict__ W,
                             char* __restrict__ Wt,
                             const unsigned* __restrict__ wsp) {
    __shared__ float tile[64][65];
    const float wmax = __uint_as_float(wsp[0]);
    const float inv  = 127.0f / wmax;
    const int n0 = blockIdx.x * 64, k0 = blockIdx.y * 64;
    const int t = threadIdx.x;
    {
        const int r = t >> 2, c0 = (t & 3) * 16;
        const float* src = W + (size_t)(k0 + r) * D_OUT + n0 + c0;
#pragma unroll
        for (int j = 0; j < 4; ++j) {
            float4 v = *(const float4*)(src + j * 4);
            tile[r][c0 + j * 4 + 0] = v.x;
            tile[r][c0 + j * 4 + 1] = v.y;
            tile[r][c0 + j * 4 + 2] = v.z;
            tile[r][c0 + j * 4 + 3] = v.w;
        }
    }
    __syncthreads();
    {
        const int n = t >> 2, kc = (t & 3) * 16;
        int4 pk;
        int* pw = (int*)&pk;
#pragma unroll
        for (int w = 0; w < 4; ++w) {
            unsigned word = 0;
#pragma unroll
            for (int j = 0; j < 4; ++j) {
                int q = (int)rintf(tile[kc + w * 4 + j][n] * inv);
                word |= ((unsigned)(unsigned char)(char)q) << (8 * j);
            }
            pw[w] = (int)word;
        }
        *(int4*)(Wt + (size_t)(n0 + n) * D_IN + k0 + kc) = pk;
    }
}

// ------- pass 3: 256x256 int8 GEMM, balanced 4-phase/tile, fixed publication
// A : [M][K] i8, Bt : [N][K] i8, C : [M][N] f32 = i32acc * (sx*ws) + bias.
// BK = 128 B; NT = 32. LDS: 2 buffers x (A 32K + B 32K).
// THE R12/R13 BUG: vmcnt is PER-WAVE but tiles are staged by ALL waves, so
// vmcnt(6) directly before reads (no barrier between) let wave w read slices
// wave v hadn't landed. Publication rule: vmcnt(N) must precede a BARRIER
// that precedes the reads (as in R4/R6/m201).
// Per tile t:
//  p1: read a03,b01,b23 | stage Ah2(t+1)->nxt | bar | Q1 | LGKM0 | bar
//  p2: stage Bh1(t+2)->cur | bar | Q2 | bar
//  p3: read a47 (reuse regs) | stage Bh2(t+2)->cur | bar | Q3 | LGKM0 | bar
//  p4: stage Ah1(t+2)->cur | bar | Q4 | VMCNT(6|0) | bar   <- publish t+1
// vmcnt ledger at p4-end: outstanding = tile(t+1) 8 (oldest) + tile(t+2) 6
// -> vmcnt(6) drains exactly tile t+1; t+2>=NT -> vmcnt(0). Prologue:
// vmcnt(6); bar publishes tile0. LGKM0 drains cross-phase reads (b23, a47)
// before the trailing barrier that precedes their region's overwrite.
__global__ __launch_bounds__(512, 2)
void gemm_kernel(const char* __restrict__ A,
                 const char* __restrict__ Bt,
                 const float* __restrict__ bias,
                 const float* __restrict__ xscale,
                 const unsigned* __restrict__ wsp,
                 float* __restrict__ C, int M) {
    constexpr int K = D_IN, N = D_OUT;
    constexpr int NT = K / 128;                // 32 K-tiles of 128 B
    __shared__ char lds[2 * 65536];

    const int tid  = threadIdx.x;
    const int lane = tid & 63;
    const int wid  = tid >> 6;
    const int wr   = wid >> 2;                 // 0..1  (M)
    const int wc   = wid & 3;                  // 0..3  (N)

    // bijective XCD-aware block swizzle
    const int nTn = N / 256;
    const int nwg = gridDim.x;
    int bid = blockIdx.x;
    int q8 = nwg >> 3, r8 = nwg & 7;
    int xcd = bid & 7, idx = bid >> 3;
    int swz = (xcd < r8 ? xcd * (q8 + 1) : r8 * (q8 + 1) + (xcd - r8) * q8) + idx;
    const int tm = swz / nTn, tn = swz % nTn;
    const int row0 = tm * 256, col0 = tn * 256;

    // half-stage offsets (16 KB): LDS dest LINEAR, XOR involution on SOURCE
    int srcOff[2], dstOff[2];
#pragma unroll
    for (int i = 0; i < 2; ++i) {
        int p  = (i * 512 + tid) * 16;         // [0, 16384)
        int sw = p ^ (((p >> 7) & 7) << 4);
        dstOff[i] = p;
        srcOff[i] = (sw >> 7) * K + (sw & 127);
    }

    const char* srcA = A  + (size_t)row0 * K;
    const char* srcB = Bt + (size_t)col0 * K;
    char* buf0 = lds;
    char* buf1 = lds + 65536;

    auto STAGEH = [&](const char* src, char* dst) {    // one 16 KB half
#pragma unroll
        for (int i = 0; i < 2; ++i)
            __builtin_amdgcn_global_load_lds((g_u32*)(src + srcOff[i]),
                                             (l_u32*)(dst + dstOff[i]), 16, 0, 0);
    };

    // ---- prologue: tile0 all 4 halves + tile1 {Bh1,Bh2,Ah1} ----
    STAGEH(srcA,               buf0);                  // Ah1(0)
    STAGEH(srcA + 128 * K,     buf0 + 16384);          // Ah2(0)
    STAGEH(srcB,               buf0 + 32768);          // Bh1(0)
    STAGEH(srcB + 128 * K,     buf0 + 49152);          // Bh2(0)
    STAGEH(srcB + 128,         buf1 + 32768);          // Bh1(1)
    STAGEH(srcB + 128 * K + 128, buf1 + 49152);        // Bh2(1)
    STAGEH(srcA + 128,         buf1);                  // Ah1(1)
    // Ah2(1) staged at p1(0)

    i32x4 acc[8][4];
#pragma unroll
    for (int m = 0; m < 8; ++m)
#pragma unroll
        for (int n = 0; n < 4; ++n) acc[m][n] = (i32x4){0, 0, 0, 0};

    // per-lane read bases (chunk XOR covers row&7) — identical to R4
    const int cp0 = (((lane >> 4) << 4)) ^ ((lane & 7) << 4);
    const int cp1 = cp0 ^ 64;
    const int aBase = (wr * 128 + (lane & 15)) * 128;
    const int bBase = (wc * 64  + (lane & 15)) * 128;

    // publish tile0: per-wave drain THEN barrier (all waves' slices landed)
    asm volatile("s_waitcnt vmcnt(6)" ::: "memory");
    __builtin_amdgcn_s_barrier();

    auto TILE = [&](int t, char* cur, char* nxt) {
        i32x4 aR[4][2], b01[2][2], b23[2][2];
        const char* cA = cur;
        const char* cB = cur + 32768;
        const bool st2 = (t + 2 < NT);

        // ---------------- p1 ----------------
#pragma unroll
        for (int m = 0; m < 4; ++m) {
            aR[m][0] = *(const i32x4*)(cA + aBase + m * 2048 + cp0);
            aR[m][1] = *(const i32x4*)(cA + aBase + m * 2048 + cp1);
        }
#pragma unroll
        for (int n = 0; n < 2; ++n) {
            b01[n][0] = *(const i32x4*)(cB + bBase + n * 2048 + cp0);
            b01[n][1] = *(const i32x4*)(cB + bBase + n * 2048 + cp1);
        }
#pragma unroll
        for (int n = 0; n < 2; ++n) {
            b23[n][0] = *(const i32x4*)(cB + bBase + 4096 + n * 2048 + cp0);
            b23[n][1] = *(const i32x4*)(cB + bBase + 4096 + n * 2048 + cp1);
        }
        if (t + 1 < NT) STAGEH(srcA + 128 * K + (t + 1) * 128, nxt + 16384); // Ah2(t+1)
        __builtin_amdgcn_s_barrier();
        __builtin_amdgcn_s_setprio(1);
#pragma unroll
        for (int m = 0; m < 4; ++m)
#pragma unroll
            for (int n = 0; n < 2; ++n) {
                acc[m][n] = __builtin_amdgcn_mfma_i32_16x16x64_i8(aR[m][0], b01[n][0], acc[m][n], 0, 0, 0);
                acc[m][n] = __builtin_amdgcn_mfma_i32_16x16x64_i8(aR[m][1], b01[n][1], acc[m][n], 0, 0, 0);
            }
        __builtin_amdgcn_s_setprio(0);
        asm volatile("s_waitcnt lgkmcnt(0)" ::: "memory");   // drain b23 reads
        __builtin_amdgcn_s_barrier();

        // ---------------- p2 ----------------
        if (st2) STAGEH(srcB + (t + 2) * 128, cur + 32768);                  // Bh1(t+2)
        __builtin_amdgcn_s_barrier();
        __builtin_amdgcn_s_setprio(1);
#pragma unroll
        for (int m = 0; m < 4; ++m)
#pragma unroll
            for (int n = 0; n < 2; ++n) {
                acc[m][n + 2] = __builtin_amdgcn_mfma_i32_16x16x64_i8(aR[m][0], b23[n][0], acc[m][n + 2], 0, 0, 0);
                acc[m][n + 2] = __builtin_amdgcn_mfma_i32_16x16x64_i8(aR[m][1], b23[n][1], acc[m][n + 2], 0, 0, 0);
            }
        __builtin_amdgcn_s_setprio(0);
        __builtin_amdgcn_s_barrier();

        // ---------------- p3 ----------------
#pragma unroll
        for (int m = 0; m < 4; ++m) {                                        // a47 (reuse regs)
            aR[m][0] = *(const i32x4*)(cA + aBase + 8192 + m * 2048 + cp0);
            aR[m][1] = *(const i32x4*)(cA + aBase + 8192 + m * 2048 + cp1);
        }
        if (st2) STAGEH(srcB + 128 * K + (t + 2) * 128, cur + 49152);        // Bh2(t+2)
        __builtin_amdgcn_s_barrier();
        __builtin_amdgcn_s_setprio(1);
#pragma unroll
        for (int m = 0; m < 4; ++m)
#pragma unroll
            for (int n = 0; n < 2; ++n) {
                acc[m + 4][n + 2] = __builtin_amdgcn_mfma_i32_16x16x64_i8(aR[m][0], b23[n][0], acc[m + 4][n + 2], 0, 0, 0);
                acc[m + 4][n + 2] = __builtin_amdgcn_mfma_i32_16x16x64_i8(aR[m][1], b23[n][1], acc[m + 4][n + 2], 0, 0, 0);
            }
        __builtin_amdgcn_s_setprio(0);
        asm volatile("s_waitcnt lgkmcnt(0)" ::: "memory");   // drain a47 reads
        __builtin_amdgcn_s_barrier();

        // ---------------- p4 ----------------
        if (st2) STAGEH(srcA + (t + 2) * 128, cur);                          // Ah1(t+2)
        __builtin_amdgcn_s_barrier();
        __builtin_amdgcn_s_setprio(1);
#pragma unroll
        for (int m = 0; m < 4; ++m)
#pragma unroll
            for (int n = 0; n < 2; ++n) {
                acc[m + 4][n] = __builtin_amdgcn_mfma_i32_16x16x64_i8(aR[m][0], b01[n][0], acc[m + 4][n], 0, 0, 0);
                acc[m + 4][n] = __builtin_amdgcn_mfma_i32_16x16x64_i8(aR[m][1], b01[n][1], acc[m + 4][n], 0, 0, 0);
            }
        __builtin_amdgcn_s_setprio(0);
        // publish tile t+1: drain (per-wave) BEFORE the trailing barrier
        if (st2) { asm volatile("s_waitcnt vmcnt(6)" ::: "memory"); }
        else     { asm volatile("s_waitcnt vmcnt(0)" ::: "memory"); }
        __builtin_amdgcn_s_barrier();
    };

    for (int t = 0; t < NT; t += 2) {
        TILE(t,     buf0, buf1);
        TILE(t + 1, buf1, buf0);
    }

    // ---- epilogue: C = acc * (sx*ws) + bias, ws = max|W|/127 ----
    const float wmax  = __uint_as_float(wsp[0]);
    const float scale = (fmaxf(xscale[0], 1e-8f) * (1.0f / 127.0f)) * (wmax * (1.0f / 127.0f));
    const int lr = (lane >> 4) * 4, lc = lane & 15;
#pragma unroll
    for (int n = 0; n < 4; ++n) {
        int col = col0 + wc * 64 + n * 16 + lc;
        float bv = bias[col];
#pragma unroll
        for (int m = 0; m < 8; ++m) {
            int rowb = row0 + wr * 128 + m * 16 + lr;
            i32x4 v = acc[m][n];
#pragma unroll
            for (int r2 = 0; r2 < 4; ++r2)
                C[(size_t)(rowb + r2) * N + col] = (float)v[r2] * scale + bv;
        }
    }
}

extern "C" void kernel_launch(void* const* d_in, const int* in_sizes, int n_in,
                              void* d_out, int out_size, void* d_ws, size_t ws_size,
                              hipStream_t stream) {
    const float* x      = (const float*)d_in[0];   // [4,2048,4096] f32
    const float* W      = (const float*)d_in[1];   // [4096,4096] f32
    const float* xscale = (const float*)d_in[2];   // scalar
    const float* bias   = (const float*)d_in[3];   // [4096] f32
    float* out = (float*)d_out;

    const int nx = in_sizes[0];            // 33554432
    const int nw = in_sizes[1];            // 16777216
    const int M  = nx / D_IN;              // 8192

    char*     xq  = (char*)d_ws;                               // 32 MiB
    char*     Wt  = (char*)d_ws + (size_t)nx;                  // 16 MiB
    unsigned* wsp = (unsigned*)((char*)d_ws + (size_t)nx + nw);// 4 B

    hipMemsetAsync(wsp, 0, 4, stream);

    int qblocks = nx / 4 / 256;            // 32768
    prep_kernel<<<1024 + qblocks, 256, 0, stream>>>(W, nw, x, xq, xscale, nx, wsp);

    dim3 tb(256);
    dim3 tg(D_OUT / 64, D_IN / 64);        // 64 x 64
    convW_kernel<<<tg, tb, 0, stream>>>(W, Wt, wsp);

    int grid = (M / 256) * (D_OUT / 256);  // 512
    gemm_kernel<<<grid, 512, 0, stream>>>(xq, Wt, bias, xscale, wsp, out, M);
}